// Round 6
// baseline (196.247 us; speedup 1.0000x reference)
//
#include <hip/hip_runtime.h>

// y[n,f] = sum_p w_table[widx[n],p] * pool[idx[n,p],f]
// pool = concat(values0, values1). N=500000, P=16, F=32, M=200000, K=10000.
// 8 lanes per neuron, one float4 per lane (full 128B row per 8-lane group,
// perfectly coalesced). Round 6: TWO neurons per thread with interleaved
// P-loops — two independent dep chains double the rolling window of
// outstanding gathers per wave WITHOUT any vmcnt(0) drain (round-4 lesson:
// batching via asm fence forces a full drain and loses; round-5 lesson:
// persistence/TLP is not the shortfall).

#define PP 16
#define FF 32

typedef float  f32x4 __attribute__((ext_vector_type(4)));

__global__ __launch_bounds__(256) void linear_gather_kernel(
    const float* __restrict__ values0,
    const float* __restrict__ values1,
    const float* __restrict__ w_table,
    const int*   __restrict__ idx,
    const int*   __restrict__ widx,
    float*       __restrict__ out,
    int N, int M)
{
    int t  = blockIdx.x * blockDim.x + threadIdx.x;
    int q  = t >> 3;          // neuron pair index
    int f4 = t & 7;           // which float4 of the 32-float row
    int n0 = q * 2;
    int n1 = n0 + 1;
    if (n0 >= N) return;
    bool has1 = (n1 < N);

    const int*   irow0 = idx + (long)n0 * PP;
    const int*   irow1 = idx + (long)n1 * PP;
    const float* wrow0 = w_table + (long)widx[n0] * PP;
    const float* wrow1 = w_table + (long)(has1 ? widx[n1] : widx[n0]) * PP;

    f32x4 acc0 = (f32x4)(0.f);
    f32x4 acc1 = (f32x4)(0.f);

#pragma unroll
    for (int p = 0; p < PP; ++p) {
        int   i0 = irow0[p];
        int   i1 = has1 ? irow1[p] : irow0[p];
        float w0 = wrow0[p];
        float w1 = wrow1[p];
        const float* s0 = (i0 < M) ? (values0 + (long)i0 * FF)
                                   : (values1 + (long)(i0 - M) * FF);
        const float* s1 = (i1 < M) ? (values0 + (long)i1 * FF)
                                   : (values1 + (long)(i1 - M) * FF);
        f32x4 v0 = *reinterpret_cast<const f32x4*>(s0 + f4 * 4);
        f32x4 v1 = *reinterpret_cast<const f32x4*>(s1 + f4 * 4);
        acc0.x = fmaf(w0, v0.x, acc0.x);
        acc0.y = fmaf(w0, v0.y, acc0.y);
        acc0.z = fmaf(w0, v0.z, acc0.z);
        acc0.w = fmaf(w0, v0.w, acc0.w);
        acc1.x = fmaf(w1, v1.x, acc1.x);
        acc1.y = fmaf(w1, v1.y, acc1.y);
        acc1.z = fmaf(w1, v1.z, acc1.z);
        acc1.w = fmaf(w1, v1.w, acc1.w);
    }

    f32x4* o = reinterpret_cast<f32x4*>(out);
    __builtin_nontemporal_store(acc0, o + (long)n0 * 8 + f4);
    if (has1)
        __builtin_nontemporal_store(acc1, o + (long)n1 * 8 + f4);
}

extern "C" void kernel_launch(void* const* d_in, const int* in_sizes, int n_in,
                              void* d_out, int out_size, void* d_ws, size_t ws_size,
                              hipStream_t stream) {
    const float* values0 = (const float*)d_in[0];
    const float* values1 = (const float*)d_in[1];
    const float* w_table = (const float*)d_in[2];
    const int*   idx     = (const int*)d_in[3];
    const int*   widx    = (const int*)d_in[4];
    float*       out     = (float*)d_out;

    const int N = in_sizes[4];          // widx has N elements
    const int M = in_sizes[0] / FF;     // values0 rows

    // 8 lanes per neuron, 2 neurons per thread.
    long npairs        = ((long)N + 1) / 2;
    long total_threads = npairs * 8;
    int  block = 256;
    int  grid  = (int)((total_threads + block - 1) / block);

    linear_gather_kernel<<<grid, block, 0, stream>>>(
        values0, values1, w_table, idx, widx, out, N, M);
}

// Round 7
// 159.537 us; speedup vs baseline: 1.2301x; 1.2301x over previous
//
#include <hip/hip_runtime.h>

// y[n,f] = sum_p w_table[widx[n],p] * pool[idx[n,p],f]
// pool = concat(values0, values1). N=500000, P=16, F=32, M=200000, K=10000.
//
// Final form (best measured: 159.4 us). 8 lanes per neuron, one float4 per
// lane -> each 8-lane group reads a full 128B pool row, perfectly coalesced;
// idx/w loads are same-address across the group (HW broadcast).
//
// Ceiling analysis (rounds 1-6): FETCH ~502 MB == replication floor
// (8 XCDs x 51 MB pool + compulsory idx/out), serviced at ~3.6 TB/s — the
// random-128B-line fabric/MSHR cap. Schedule variants tested and rejected:
// forced 16-deep MLP batch (vmcnt(0) drain, -17%), persistent grid (-11%),
// 2-neuron ILP (VGPR 100, occ 22%, -30%). Throughput saturates above ~60%
// occupancy; this simple schedule is on the ceiling.

#define PP 16
#define FF 32

__global__ __launch_bounds__(256) void linear_gather_kernel(
    const float* __restrict__ values0,
    const float* __restrict__ values1,
    const float* __restrict__ w_table,
    const int*   __restrict__ idx,
    const int*   __restrict__ widx,
    float*       __restrict__ out,
    int N, int M)
{
    int t = blockIdx.x * blockDim.x + threadIdx.x;
    int n  = t >> 3;   // 8 lanes per neuron
    int f4 = t & 7;    // which float4 of the 32-float row
    if (n >= N) return;

    const float* wrow = w_table + (long)widx[n] * PP;
    const int*   irow = idx + (long)n * PP;

    float4 acc = make_float4(0.f, 0.f, 0.f, 0.f);
#pragma unroll
    for (int p = 0; p < PP; ++p) {
        int   i = irow[p];                 // same addr across the 8 lanes -> broadcast
        float w = wrow[p];                 // same addr across the 8 lanes -> broadcast
        const float* src = (i < M) ? (values0 + (long)i * FF)
                                   : (values1 + (long)(i - M) * FF);
        float4 v = *reinterpret_cast<const float4*>(src + f4 * 4);
        acc.x += w * v.x;
        acc.y += w * v.y;
        acc.z += w * v.z;
        acc.w += w * v.w;
    }
    reinterpret_cast<float4*>(out)[(long)n * 8 + f4] = acc;
}

extern "C" void kernel_launch(void* const* d_in, const int* in_sizes, int n_in,
                              void* d_out, int out_size, void* d_ws, size_t ws_size,
                              hipStream_t stream) {
    const float* values0 = (const float*)d_in[0];
    const float* values1 = (const float*)d_in[1];
    const float* w_table = (const float*)d_in[2];
    const int*   idx     = (const int*)d_in[3];
    const int*   widx    = (const int*)d_in[4];
    float*       out     = (float*)d_out;

    const int N = in_sizes[4];          // widx has N elements
    const int M = in_sizes[0] / FF;     // values0 rows

    long total_threads = (long)N * 8;
    int  block = 256;
    int  grid  = (int)((total_threads + block - 1) / block);

    linear_gather_kernel<<<grid, block, 0, stream>>>(
        values0, values1, w_table, idx, widx, out, N, M);
}